// Round 8
// baseline (446.031 us; speedup 1.0000x reference)
//
#include <hip/hip_runtime.h>
#include <stdint.h>
#include <string.h>

// ---------------------------------------------------------------------------
// JAX threefry2x32 (exact port of jax/_src/prng.py lowering)
// ---------------------------------------------------------------------------
__host__ __device__ inline uint32_t rotl32(uint32_t x, int r) {
    return (x << r) | (x >> (32 - r));
}

__host__ __device__ inline void tf2x32(uint32_t k0, uint32_t k1,
                                       uint32_t x0, uint32_t x1,
                                       uint32_t& o0, uint32_t& o1) {
    uint32_t ks0 = k0, ks1 = k1, ks2 = k0 ^ k1 ^ 0x1BD11BDAu;
    x0 += ks0; x1 += ks1;
#define TF_R4(a,b,c,d) \
    x0 += x1; x1 = rotl32(x1,a); x1 ^= x0; \
    x0 += x1; x1 = rotl32(x1,b); x1 ^= x0; \
    x0 += x1; x1 = rotl32(x1,c); x1 ^= x0; \
    x0 += x1; x1 = rotl32(x1,d); x1 ^= x0;
    TF_R4(13,15,26,6)  x0 += ks1; x1 += ks2 + 1u;
    TF_R4(17,29,16,24) x0 += ks2; x1 += ks0 + 2u;
    TF_R4(13,15,26,6)  x0 += ks0; x1 += ks1 + 3u;
    TF_R4(17,29,16,24) x0 += ks1; x1 += ks2 + 4u;
    TF_R4(13,15,26,6)  x0 += ks2; x1 += ks0 + 5u;
#undef TF_R4
    o0 = x0; o1 = x1;
}

// f16 pack/unpack helpers (IEEE half; values here are far inside f16 range)
__device__ inline unsigned pk2h(float a, float b) {
    _Float16 ha = (_Float16)a, hb = (_Float16)b;
    unsigned short ua, ub;
    __builtin_memcpy(&ua, &ha, 2);
    __builtin_memcpy(&ub, &hb, 2);
    return (unsigned)ua | ((unsigned)ub << 16);
}
__device__ inline float lo16(unsigned u) {
    unsigned short s = (unsigned short)(u & 0xffffu);
    _Float16 h; __builtin_memcpy(&h, &s, 2);
    return (float)h;
}
__device__ inline float hi16(unsigned u) {
    unsigned short s = (unsigned short)(u >> 16);
    _Float16 h; __builtin_memcpy(&h, &s, 2);
    return (float)h;
}

// clang ext-vector types
typedef float fx4 __attribute__((ext_vector_type(4)));
typedef unsigned ux4 __attribute__((ext_vector_type(4)));
typedef _Float16 h16x8 __attribute__((ext_vector_type(8)));
typedef float f32x4 __attribute__((ext_vector_type(4)));

#define CSR_CAP 48     // per-node CSR capacity (Poisson(16); P(>48)~1e-11)
#define NBIN 8         // one bin per XCD (blockIdx % 8 -> XCD, measured m09)
#define FILL_EPB 2048  // edges scanned per fill block (256 thr x 8)

// ---------------------------------------------------------------------------
// fused build kernel: grid ranges [binned-fill | mask | cvt | wcvt]
// ---------------------------------------------------------------------------
__global__ __launch_bounds__(256) void k_build(
        const int* __restrict__ ei, unsigned* __restrict__ cnt,
        unsigned* __restrict__ csr,
        unsigned long long* __restrict__ m1, unsigned long long* __restrict__ m2,
        const float* __restrict__ x, unsigned* __restrict__ xb,
        const float* __restrict__ w1, const float* __restrict__ w2,
        _Float16* __restrict__ wt1, _Float16* __restrict__ wt2,
        unsigned k1a, unsigned k1b, unsigned k2a, unsigned k2b,
        int E, int N, int binw, int total, int FB, int MB, int CB) {
    int b = blockIdx.x;
    if (b < FB) {   // ---- binned fill ----
        int bin = b & (NBIN - 1);
        int chunk = b >> 3;
        int lo = bin * binw;
        int hi = lo + binw;   // [lo, hi) node range owned by this bin/XCD
        int e0 = chunk * FILL_EPB + (int)threadIdx.x;
#pragma unroll
        for (int it = 0; it < FILL_EPB / 256; ++it) {
            int e = e0 + it * 256;
            if (e < E) {
                int c = __builtin_nontemporal_load(ei + (size_t)E + e);
                if (c >= lo && c < hi) {
                    int r = __builtin_nontemporal_load(ei + e);
                    if ((unsigned)r < (unsigned)N) {
                        unsigned slot = atomicAdd(&cnt[c], 1u);
                        if (slot < (unsigned)CSR_CAP)
                            csr[(size_t)(unsigned)c * CSR_CAP + slot] = (unsigned)r;
                    }
                }
            }
        }
        return;
    }
    b -= FB;
    if (b < MB) {   // ---- mask ----
        int i = b * 256 + (int)threadIdx.x;   // [0, 2*total)
        if (i < 2 * total) {
            int idx = i;
            unsigned ka = k1a, kb = k1b;
            unsigned long long* m = m1;
            if (i >= total) { idx = i - total; ka = k2a; kb = k2b; m = m2; }
            uint32_t o0, o1;
            tf2x32(ka, kb, 0u, (uint32_t)idx, o0, o1);
            bool keep = (((o0 ^ o1) >> 9) < 7549747u);
            unsigned long long bal = __ballot(keep);
            if ((threadIdx.x & 63) == 0)
                __builtin_nontemporal_store(bal, m + (idx >> 6));
        }
        return;
    }
    b -= MB;
    if (b < CB) {   // ---- cvt: x f32 -> f16 table ----
        int i = b * 256 + (int)threadIdx.x;   // [0, total/8)
        if (i < (total >> 3)) {
            const fx4* src = (const fx4*)(x + (size_t)i * 8);
            fx4 a = __builtin_nontemporal_load(src);
            fx4 bb = __builtin_nontemporal_load(src + 1);
            ux4 v;
            v.x = pk2h(a.x, a.y);
            v.y = pk2h(a.z, a.w);
            v.z = pk2h(bb.x, bb.y);
            v.w = pk2h(bb.z, bb.w);
            __builtin_nontemporal_store(v, (ux4*)xb + i);
        }
        return;
    }
    b -= CB;        // ---- wcvt: WT[c][k] = (f16)W[k][c], 2 matrices ----
    int idx = b * 256 + (int)threadIdx.x;     // [0, 32768)
    int mat = idx >> 14;
    int e2 = idx & 16383;
    int c = e2 >> 7, k = e2 & 127;
    const float* W = mat ? w2 : w1;
    _Float16* WT = mat ? wt2 : wt1;
    WT[(size_t)c * 128 + k] = (_Float16)W[(size_t)k * 128 + c];
}

__global__ void k_dinv(const unsigned* __restrict__ cnt, float* __restrict__ dinv, int N) {
    int n = blockIdx.x * blockDim.x + threadIdx.x;
    if (n >= N) return;
    dinv[n] = rsqrtf((float)cnt[n] + 1.0f);   // deg includes self-loop
}

// ---------------------------------------------------------------------------
// fused layer kernel: agg -> LDS -> MFMA gemm -> epilogue -> store
//  block = 64 nodes, 4 waves; wave w owns rows [w*16, w*16+16).
//  phase 1 (agg): per node, 4 edge-slots x (16 lanes x 8 f16 ch) gather from
//    the f16 table; shfl-reduce; packed-f16 row -> LDS hl[64][136] (stride
//    136 f16 = 68 dw -> 2-way bank alias, free). Wave writes ONLY its rows.
//  phase 2 (MFMA): A-frags ds_read from the wave's OWN rows (no barrier
//    needed between phases); B-frags from pre-transposed WT (L1-resident).
//  then: barrier -> acc transpose to S[64][130] f32 -> barrier -> fused
//  bias/dropout/prelu epilogue -> coalesced store (f16 table or f32 out).
// ---------------------------------------------------------------------------
#define UPK_FMA(c, uu)                                   \
    acc[0] = fmaf(c, lo16((uu).x), acc[0]);              \
    acc[1] = fmaf(c, hi16((uu).x), acc[1]);              \
    acc[2] = fmaf(c, lo16((uu).y), acc[2]);              \
    acc[3] = fmaf(c, hi16((uu).y), acc[3]);              \
    acc[4] = fmaf(c, lo16((uu).z), acc[4]);              \
    acc[5] = fmaf(c, hi16((uu).z), acc[5]);              \
    acc[6] = fmaf(c, lo16((uu).w), acc[6]);              \
    acc[7] = fmaf(c, hi16((uu).w), acc[7]);

template <int OUT_HALF>
__global__ __launch_bounds__(256) void k_layer(
        const unsigned short* __restrict__ in,   // f16 gather table [N][128]
        const _Float16* __restrict__ WT,         // f16 [col][k]
        const float* __restrict__ bias, const float* __restrict__ alpha,
        const unsigned long long* __restrict__ mask,
        const float* __restrict__ dinv, const unsigned* __restrict__ cnt,
        const unsigned* __restrict__ csr,
        void* outv, int n) {
    __shared__ float S[64 * 130];       // 33.28 KB; hl[64][68] u32 aliased inside
    unsigned* hl = (unsigned*)S;
    int t = threadIdx.x;
    int rowbase = blockIdx.x * 64;
    int w = t >> 6, l = t & 63;
    int slot = l >> 4;                  // 4 edge slots
    int lm = l & 15;
    int ci = lm << 3;                   // 8-channel group (f16)

    // ---- phase 1: aggregate 16 nodes owned by this wave ----
    for (int i = 0; i < 16; ++i) {
        int node = rowbase + w * 16 + i;
        float acc[8];
#pragma unroll
        for (int j = 0; j < 8; j++) acc[j] = 0.f;
        if (node < n) {
            float dn = dinv[node];
            unsigned ecnt = cnt[node];
            if (ecnt > (unsigned)CSR_CAP) ecnt = (unsigned)CSR_CAP;
            unsigned cntS = (ecnt > (unsigned)slot) ? ((ecnt - (unsigned)slot + 3u) >> 2) : 0u;
            unsigned pairs = cntS >> 1;
            size_t ee = (size_t)node * CSR_CAP + (unsigned)slot;
#pragma unroll 2
            for (unsigned it = 0; it < pairs; ++it) {
                unsigned ra = csr[ee];
                unsigned rb = csr[ee + 4];
                float da = dinv[ra];
                float db = dinv[rb];
                uint4 ua = *(const uint4*)(in + ((size_t)ra << 7) + ci);
                uint4 ub = *(const uint4*)(in + ((size_t)rb << 7) + ci);
                float ca = dn * da;
                float cb = dn * db;
                UPK_FMA(ca, ua)
                UPK_FMA(cb, ub)
                ee += 8;
            }
            if (cntS & 1u) {
                unsigned ra = csr[ee];
                float da = dinv[ra];
                uint4 ua = *(const uint4*)(in + ((size_t)ra << 7) + ci);
                float ca = dn * da;
                UPK_FMA(ca, ua)
            }
        }
        // reduce the 4 edge-slots
#pragma unroll
        for (int j = 0; j < 8; j++) acc[j] += __shfl_xor(acc[j], 16);
#pragma unroll
        for (int j = 0; j < 8; j++) acc[j] += __shfl_xor(acc[j], 32);
        if (slot == 0) {
            if (node < n) {   // self-loop term
                uint4 sv = *(const uint4*)(in + ((size_t)node << 7) + ci);
                float dn = dinv[node];
                float dd = dn * dn;
                UPK_FMA(dd, sv)
            }
            uint4 o;
            o.x = pk2h(acc[0], acc[1]);
            o.y = pk2h(acc[2], acc[3]);
            o.z = pk2h(acc[4], acc[5]);
            o.w = pk2h(acc[6], acc[7]);
            *(uint4*)(hl + (size_t)(w * 16 + i) * 68 + lm * 4) = o;
        }
    }

    // ---- phase 2: MFMA on own rows (no barrier: wave reads only what it wrote)
    int kq = l >> 4;
    f32x4 facc[8];
#pragma unroll
    for (int f = 0; f < 8; f++) facc[f] = (f32x4){0.f, 0.f, 0.f, 0.f};
#pragma unroll
    for (int kk = 0; kk < 4; kk++) {
        h16x8 a = *(const h16x8*)(hl + (size_t)(w * 16 + lm) * 68 + kq * 4 + kk * 16);
#pragma unroll
        for (int f = 0; f < 8; f++) {
            h16x8 bfr = *(const h16x8*)(WT + (size_t)(f * 16 + lm) * 128 + kk * 32 + kq * 8);
            facc[f] = __builtin_amdgcn_mfma_f32_16x16x32_f16(a, bfr, facc[f], 0, 0, 0);
        }
    }
    __syncthreads();   // all waves done reading hl before S overwrite
    {   // acc -> S[row][col] (own 16-row stripe)
        int r0 = w * 16 + kq * 4;
#pragma unroll
        for (int f = 0; f < 8; f++)
#pragma unroll
            for (int j = 0; j < 4; j++)
                S[(r0 + j) * 130 + f * 16 + lm] = facc[f][j];
    }
    __syncthreads();
    {   // fused epilogue + coalesced store; thread: row r, col range q*32..+32
        int r = t >> 2, q = t & 3;
        int rg = rowbase + r;
        if (rg < n) {
            unsigned long long wm = mask[((size_t)rg << 1) + (q >> 1)];
            int shift = (q & 1) * 32;
            if (OUT_HALF) {
                unsigned short* ob = (unsigned short*)outv;
                uint4* dst = (uint4*)(ob + ((size_t)rg << 7) + q * 32);
#pragma unroll
                for (int i = 0; i < 4; i++) {
                    float v[8];
#pragma unroll
                    for (int j = 0; j < 8; j++) {
                        int c = q * 32 + i * 8 + j;
                        float vv = S[r * 130 + c] + bias[c];
                        bool keep = (wm >> (shift + i * 8 + j)) & 1ull;
                        vv = keep ? vv * (1.0f / 0.9f) : 0.0f;
                        v[j] = (vv >= 0.f) ? vv : alpha[c] * vv;
                    }
                    uint4 o;
                    o.x = pk2h(v[0], v[1]);
                    o.y = pk2h(v[2], v[3]);
                    o.z = pk2h(v[4], v[5]);
                    o.w = pk2h(v[6], v[7]);
                    dst[i] = o;
                }
            } else {
                float4* dst = (float4*)((float*)outv + ((size_t)rg << 7) + q * 32);
#pragma unroll
                for (int i = 0; i < 8; i++) {
                    float v[4];
#pragma unroll
                    for (int j = 0; j < 4; j++) {
                        int c = q * 32 + i * 4 + j;
                        float vv = S[r * 130 + c] + bias[c];
                        bool keep = (wm >> (shift + i * 4 + j)) & 1ull;
                        vv = keep ? vv * (1.0f / 0.9f) : 0.0f;
                        v[j] = (vv >= 0.f) ? vv : alpha[c] * vv;
                    }
                    dst[i] = make_float4(v[0], v[1], v[2], v[3]);
                }
            }
        }
    }
}

// ---------------------------------------------------------------------------
extern "C" void kernel_launch(void* const* d_in, const int* in_sizes, int n_in,
                              void* d_out, int out_size, void* d_ws, size_t ws_size,
                              hipStream_t stream) {
    const float* x  = (const float*)d_in[0];
    const int*   ei = (const int*)d_in[1];     // [2][E] int32
    const float* W1 = (const float*)d_in[2];
    const float* b1 = (const float*)d_in[3];
    const float* W2 = (const float*)d_in[4];
    const float* b2 = (const float*)d_in[5];
    const float* al = (const float*)d_in[6];
    int N = in_sizes[0] / 128;
    int E = in_sizes[1] / 2;
    float* out = (float*)d_out;

    char* p = (char*)d_ws;
    unsigned short* xb = (unsigned short*)p;   p += (size_t)N * 128 * 2;  // x table
    unsigned short* ab = (unsigned short*)p;   p += (size_t)N * 128 * 2;  // h1 table
    unsigned* cnt = (unsigned*)p;              p += (size_t)N * 4;
    float* dinv = (float*)p;                   p += (size_t)N * 4;
    unsigned* csr = (unsigned*)p;              p += (size_t)N * CSR_CAP * 4;
    unsigned long long* m1 = (unsigned long long*)p;  p += ((size_t)N * 128 / 64) * 8;
    unsigned long long* m2 = (unsigned long long*)p;  p += ((size_t)N * 128 / 64) * 8;
    _Float16* wt1 = (_Float16*)p;              p += 128 * 128 * 2;
    _Float16* wt2 = (_Float16*)p;

    hipMemsetAsync(cnt, 0, (size_t)N * 4, stream);

    // dropout keys: dk_i = TF(key(42), (0, i))  (partitionable fold-like split)
    uint32_t dk1a, dk1b, dk2a, dk2b;
    tf2x32(0u, 42u, 0u, 0u, dk1a, dk1b);
    tf2x32(0u, 42u, 0u, 1u, dk2a, dk2b);

    int total = N * 128;
    int binw = (N + NBIN - 1) / NBIN;
    int chunks = (E + FILL_EPB - 1) / FILL_EPB;
    int FB = NBIN * chunks;
    int MB = (2 * total + 255) / 256;
    int CB = (total / 8 + 255) / 256;
    int WB = (2 * 128 * 128 + 255) / 256;
    k_build<<<FB + MB + CB + WB, 256, 0, stream>>>(ei, cnt, csr, m1, m2,
                                                   x, (unsigned*)xb,
                                                   W1, W2, wt1, wt2,
                                                   dk1a, dk1b, dk2a, dk2b,
                                                   E, N, binw, total, FB, MB, CB);
    k_dinv<<<(N + 255) / 256, 256, 0, stream>>>(cnt, dinv, N);

    int LB = (N + 63) / 64;
    // layer 1: fused agg+gemm: gather xb -> h1 table (f16) in ab
    k_layer<1><<<LB, 256, 0, stream>>>(xb, wt1, b1, al, m1, dinv, cnt, csr, ab, N);
    // layer 2: fused agg+gemm: gather ab -> d_out (f32)
    k_layer<0><<<LB, 256, 0, stream>>>(ab, wt2, b2, al, m2, dinv, cnt, csr, out, N);
}

// Round 9
// 397.063 us; speedup vs baseline: 1.1233x; 1.1233x over previous
//
#include <hip/hip_runtime.h>
#include <stdint.h>
#include <string.h>

// ---------------------------------------------------------------------------
// JAX threefry2x32 (exact port of jax/_src/prng.py lowering)
// ---------------------------------------------------------------------------
__host__ __device__ inline uint32_t rotl32(uint32_t x, int r) {
    return (x << r) | (x >> (32 - r));
}

__host__ __device__ inline void tf2x32(uint32_t k0, uint32_t k1,
                                       uint32_t x0, uint32_t x1,
                                       uint32_t& o0, uint32_t& o1) {
    uint32_t ks0 = k0, ks1 = k1, ks2 = k0 ^ k1 ^ 0x1BD11BDAu;
    x0 += ks0; x1 += ks1;
#define TF_R4(a,b,c,d) \
    x0 += x1; x1 = rotl32(x1,a); x1 ^= x0; \
    x0 += x1; x1 = rotl32(x1,b); x1 ^= x0; \
    x0 += x1; x1 = rotl32(x1,c); x1 ^= x0; \
    x0 += x1; x1 = rotl32(x1,d); x1 ^= x0;
    TF_R4(13,15,26,6)  x0 += ks1; x1 += ks2 + 1u;
    TF_R4(17,29,16,24) x0 += ks2; x1 += ks0 + 2u;
    TF_R4(13,15,26,6)  x0 += ks0; x1 += ks1 + 3u;
    TF_R4(17,29,16,24) x0 += ks1; x1 += ks2 + 4u;
    TF_R4(13,15,26,6)  x0 += ks2; x1 += ks0 + 5u;
#undef TF_R4
    o0 = x0; o1 = x1;
}

// f16 pack/unpack helpers (IEEE half; values here are far inside f16 range)
__device__ inline unsigned pk2h(float a, float b) {
    _Float16 ha = (_Float16)a, hb = (_Float16)b;
    unsigned short ua, ub;
    __builtin_memcpy(&ua, &ha, 2);
    __builtin_memcpy(&ub, &hb, 2);
    return (unsigned)ua | ((unsigned)ub << 16);
}
__device__ inline unsigned short h16bits(float a) {
    _Float16 h = (_Float16)a;
    unsigned short u; __builtin_memcpy(&u, &h, 2);
    return u;
}
__device__ inline float lo16(unsigned u) {
    unsigned short s = (unsigned short)(u & 0xffffu);
    _Float16 h; __builtin_memcpy(&h, &s, 2);
    return (float)h;
}
__device__ inline float hi16(unsigned u) {
    unsigned short s = (unsigned short)(u >> 16);
    _Float16 h; __builtin_memcpy(&h, &s, 2);
    return (float)h;
}

// clang ext-vector types
typedef float fx4 __attribute__((ext_vector_type(4)));
typedef unsigned ux4 __attribute__((ext_vector_type(4)));
typedef _Float16 h16x8 __attribute__((ext_vector_type(8)));
typedef float f32x4 __attribute__((ext_vector_type(4)));

#define CSR_CAP 48     // per-node CSR capacity (Poisson(16); P(>48)~1e-11)
#define NBIN 8         // one bin per XCD (blockIdx % 8 -> XCD, measured m09)
#define FILL_EPB 2048  // edges scanned per fill block (256 thr x 8)

// ---------------------------------------------------------------------------
// fused build kernel: grid ranges [binned-fill | mask | cvt | wcvt]
// ---------------------------------------------------------------------------
__global__ __launch_bounds__(256) void k_build(
        const int* __restrict__ ei, unsigned* __restrict__ cnt,
        unsigned* __restrict__ csr,
        unsigned long long* __restrict__ m1, unsigned long long* __restrict__ m2,
        const float* __restrict__ x, unsigned* __restrict__ xb,
        const float* __restrict__ w1, const float* __restrict__ w2,
        _Float16* __restrict__ wt1, _Float16* __restrict__ wt2,
        unsigned k1a, unsigned k1b, unsigned k2a, unsigned k2b,
        int E, int N, int binw, int total, int FB, int MB, int CB) {
    int b = blockIdx.x;
    if (b < FB) {   // ---- binned fill ----
        int bin = b & (NBIN - 1);
        int chunk = b >> 3;
        int lo = bin * binw;
        int hi = lo + binw;   // [lo, hi) node range owned by this bin/XCD
        int e0 = chunk * FILL_EPB + (int)threadIdx.x;
#pragma unroll
        for (int it = 0; it < FILL_EPB / 256; ++it) {
            int e = e0 + it * 256;
            if (e < E) {
                int c = __builtin_nontemporal_load(ei + (size_t)E + e);
                if (c >= lo && c < hi) {
                    int r = __builtin_nontemporal_load(ei + e);
                    if ((unsigned)r < (unsigned)N) {
                        unsigned slot = atomicAdd(&cnt[c], 1u);
                        if (slot < (unsigned)CSR_CAP)
                            csr[(size_t)(unsigned)c * CSR_CAP + slot] = (unsigned)r;
                    }
                }
            }
        }
        return;
    }
    b -= FB;
    if (b < MB) {   // ---- mask ----
        int i = b * 256 + (int)threadIdx.x;   // [0, 2*total)
        if (i < 2 * total) {
            int idx = i;
            unsigned ka = k1a, kb = k1b;
            unsigned long long* m = m1;
            if (i >= total) { idx = i - total; ka = k2a; kb = k2b; m = m2; }
            uint32_t o0, o1;
            tf2x32(ka, kb, 0u, (uint32_t)idx, o0, o1);
            bool keep = (((o0 ^ o1) >> 9) < 7549747u);
            unsigned long long bal = __ballot(keep);
            if ((threadIdx.x & 63) == 0)
                __builtin_nontemporal_store(bal, m + (idx >> 6));
        }
        return;
    }
    b -= MB;
    if (b < CB) {   // ---- cvt: x f32 -> f16 table ----
        int i = b * 256 + (int)threadIdx.x;   // [0, total/8)
        if (i < (total >> 3)) {
            const fx4* src = (const fx4*)(x + (size_t)i * 8);
            fx4 a = __builtin_nontemporal_load(src);
            fx4 bb = __builtin_nontemporal_load(src + 1);
            ux4 v;
            v.x = pk2h(a.x, a.y);
            v.y = pk2h(a.z, a.w);
            v.z = pk2h(bb.x, bb.y);
            v.w = pk2h(bb.z, bb.w);
            __builtin_nontemporal_store(v, (ux4*)xb + i);
        }
        return;
    }
    b -= CB;        // ---- wcvt: WT[c][k] = (f16)W[k][c], 2 matrices ----
    int idx = b * 256 + (int)threadIdx.x;     // [0, 32768)
    int mat = idx >> 14;
    int e2 = idx & 16383;
    int c = e2 >> 7, k = e2 & 127;
    const float* W = mat ? w2 : w1;
    _Float16* WT = mat ? wt2 : wt1;
    WT[(size_t)c * 128 + k] = (_Float16)W[(size_t)k * 128 + c];
}

__global__ void k_dinv(const unsigned* __restrict__ cnt, float* __restrict__ dinv, int N) {
    int n = blockIdx.x * blockDim.x + threadIdx.x;
    if (n >= N) return;
    dinv[n] = rsqrtf((float)cnt[n] + 1.0f);   // deg includes self-loop
}

// ---------------------------------------------------------------------------
// fused layer kernel: agg -> LDS(f16) -> MFMA -> reg-direct epilogue -> store
//  block = 64 nodes, 4 waves; wave w owns rows [w*16, w*16+16).
//  phase 1 (agg): per node, 4 edge-slots x (16 lanes x 8 f16 ch) gather;
//    shfl-reduce; packed-f16 row -> LDS hl[64][68] u32 (17.4 KB only).
//  phase 2 (MFMA): A-frags from the wave's OWN hl rows (wave-private ->
//    NO barriers anywhere); B-frags from pre-transposed WT (L1-resident).
//  phase 3: epilogue straight from D-fragment registers using the verified
//    mapping col=lane&15, row=(lane>>4)*4+reg; stores in 64B (f32) / 32B
//    (f16) segments. No f32 LDS transpose stage -> occupancy restored.
// ---------------------------------------------------------------------------
#define UPK_FMA(c, uu)                                   \
    acc[0] = fmaf(c, lo16((uu).x), acc[0]);              \
    acc[1] = fmaf(c, hi16((uu).x), acc[1]);              \
    acc[2] = fmaf(c, lo16((uu).y), acc[2]);              \
    acc[3] = fmaf(c, hi16((uu).y), acc[3]);              \
    acc[4] = fmaf(c, lo16((uu).z), acc[4]);              \
    acc[5] = fmaf(c, hi16((uu).z), acc[5]);              \
    acc[6] = fmaf(c, lo16((uu).w), acc[6]);              \
    acc[7] = fmaf(c, hi16((uu).w), acc[7]);

template <int OUT_HALF>
__global__ __launch_bounds__(256) void k_layer(
        const unsigned short* __restrict__ in,   // f16 gather table [N][128]
        const _Float16* __restrict__ WT,         // f16 [col][k]
        const float* __restrict__ bias, const float* __restrict__ alpha,
        const unsigned long long* __restrict__ mask,
        const float* __restrict__ dinv, const unsigned* __restrict__ cnt,
        const unsigned* __restrict__ csr,
        void* outv, int n) {
    __shared__ unsigned hl[64 * 68];    // 17.4 KB packed-f16 rows, stride 68 dw
    int t = threadIdx.x;
    int rowbase = blockIdx.x * 64;
    int w = t >> 6, l = t & 63;
    int slot = l >> 4;                  // 4 edge slots
    int lm = l & 15;
    int ci = lm << 3;                   // 8-channel group (f16)

    // ---- phase 1: aggregate 16 nodes owned by this wave ----
    for (int i = 0; i < 16; ++i) {
        int node = rowbase + w * 16 + i;
        float acc[8];
#pragma unroll
        for (int j = 0; j < 8; j++) acc[j] = 0.f;
        if (node < n) {
            float dn = dinv[node];
            unsigned ecnt = cnt[node];
            if (ecnt > (unsigned)CSR_CAP) ecnt = (unsigned)CSR_CAP;
            unsigned cntS = (ecnt > (unsigned)slot) ? ((ecnt - (unsigned)slot + 3u) >> 2) : 0u;
            unsigned pairs = cntS >> 1;
            size_t ee = (size_t)node * CSR_CAP + (unsigned)slot;
#pragma unroll 2
            for (unsigned it = 0; it < pairs; ++it) {
                unsigned ra = csr[ee];
                unsigned rb = csr[ee + 4];
                float da = dinv[ra];
                float db = dinv[rb];
                uint4 ua = *(const uint4*)(in + ((size_t)ra << 7) + ci);
                uint4 ub = *(const uint4*)(in + ((size_t)rb << 7) + ci);
                float ca = dn * da;
                float cb = dn * db;
                UPK_FMA(ca, ua)
                UPK_FMA(cb, ub)
                ee += 8;
            }
            if (cntS & 1u) {
                unsigned ra = csr[ee];
                float da = dinv[ra];
                uint4 ua = *(const uint4*)(in + ((size_t)ra << 7) + ci);
                float ca = dn * da;
                UPK_FMA(ca, ua)
            }
        }
        // reduce the 4 edge-slots
#pragma unroll
        for (int j = 0; j < 8; j++) acc[j] += __shfl_xor(acc[j], 16);
#pragma unroll
        for (int j = 0; j < 8; j++) acc[j] += __shfl_xor(acc[j], 32);
        if (slot == 0) {
            if (node < n) {   // self-loop term
                uint4 sv = *(const uint4*)(in + ((size_t)node << 7) + ci);
                float dn = dinv[node];
                float dd = dn * dn;
                UPK_FMA(dd, sv)
            }
            uint4 o;
            o.x = pk2h(acc[0], acc[1]);
            o.y = pk2h(acc[2], acc[3]);
            o.z = pk2h(acc[4], acc[5]);
            o.w = pk2h(acc[6], acc[7]);
            *(uint4*)(hl + (size_t)(w * 16 + i) * 68 + lm * 4) = o;
        }
    }

    // ---- phase 2: MFMA on own rows (wave-private hl -> no barrier) ----
    int kq = l >> 4;
    f32x4 facc[8];
#pragma unroll
    for (int f = 0; f < 8; f++) facc[f] = (f32x4){0.f, 0.f, 0.f, 0.f};
#pragma unroll
    for (int kk = 0; kk < 4; kk++) {
        h16x8 a = *(const h16x8*)(hl + (size_t)(w * 16 + lm) * 68 + kq * 4 + kk * 16);
#pragma unroll
        for (int f = 0; f < 8; f++) {
            h16x8 bfr = *(const h16x8*)(WT + (size_t)(f * 16 + lm) * 128 + kk * 32 + kq * 8);
            facc[f] = __builtin_amdgcn_mfma_f32_16x16x32_f16(a, bfr, facc[f], 0, 0, 0);
        }
    }

    // ---- phase 3: epilogue direct from D-fragments ----
    // lane l, frag f, reg j -> (row = rowbase + w*16 + kq*4 + j, col = f*16+lm)
#pragma unroll
    for (int j = 0; j < 4; j++) {
        int rg = rowbase + w * 16 + kq * 4 + j;
        if (rg < n) {
            unsigned long long wm0 = mask[(size_t)rg << 1];
            unsigned long long wm1 = mask[((size_t)rg << 1) + 1];
#pragma unroll
            for (int f = 0; f < 8; f++) {
                int c = f * 16 + lm;
                float v = facc[f][j] + bias[c];
                unsigned long long wmw = (f < 4) ? wm0 : wm1;
                bool keep = (wmw >> (c & 63)) & 1ull;
                v = keep ? v * (1.0f / 0.9f) : 0.0f;
                float al = alpha[c];
                v = (v >= 0.f) ? v : al * v;
                if (OUT_HALF)
                    ((unsigned short*)outv)[(size_t)rg * 128 + c] = h16bits(v);
                else
                    ((float*)outv)[(size_t)rg * 128 + c] = v;
            }
        }
    }
}

// ---------------------------------------------------------------------------
extern "C" void kernel_launch(void* const* d_in, const int* in_sizes, int n_in,
                              void* d_out, int out_size, void* d_ws, size_t ws_size,
                              hipStream_t stream) {
    const float* x  = (const float*)d_in[0];
    const int*   ei = (const int*)d_in[1];     // [2][E] int32
    const float* W1 = (const float*)d_in[2];
    const float* b1 = (const float*)d_in[3];
    const float* W2 = (const float*)d_in[4];
    const float* b2 = (const float*)d_in[5];
    const float* al = (const float*)d_in[6];
    int N = in_sizes[0] / 128;
    int E = in_sizes[1] / 2;
    float* out = (float*)d_out;

    char* p = (char*)d_ws;
    unsigned short* xb = (unsigned short*)p;   p += (size_t)N * 128 * 2;  // x table
    unsigned short* ab = (unsigned short*)p;   p += (size_t)N * 128 * 2;  // h1 table
    unsigned* cnt = (unsigned*)p;              p += (size_t)N * 4;
    float* dinv = (float*)p;                   p += (size_t)N * 4;
    unsigned* csr = (unsigned*)p;              p += (size_t)N * CSR_CAP * 4;
    unsigned long long* m1 = (unsigned long long*)p;  p += ((size_t)N * 128 / 64) * 8;
    unsigned long long* m2 = (unsigned long long*)p;  p += ((size_t)N * 128 / 64) * 8;
    _Float16* wt1 = (_Float16*)p;              p += 128 * 128 * 2;
    _Float16* wt2 = (_Float16*)p;

    hipMemsetAsync(cnt, 0, (size_t)N * 4, stream);

    // dropout keys: dk_i = TF(key(42), (0, i))  (partitionable fold-like split)
    uint32_t dk1a, dk1b, dk2a, dk2b;
    tf2x32(0u, 42u, 0u, 0u, dk1a, dk1b);
    tf2x32(0u, 42u, 0u, 1u, dk2a, dk2b);

    int total = N * 128;
    int binw = (N + NBIN - 1) / NBIN;
    int chunks = (E + FILL_EPB - 1) / FILL_EPB;
    int FB = NBIN * chunks;
    int MB = (2 * total + 255) / 256;
    int CB = (total / 8 + 255) / 256;
    int WB = (2 * 128 * 128 + 255) / 256;
    k_build<<<FB + MB + CB + WB, 256, 0, stream>>>(ei, cnt, csr, m1, m2,
                                                   x, (unsigned*)xb,
                                                   W1, W2, wt1, wt2,
                                                   dk1a, dk1b, dk2a, dk2b,
                                                   E, N, binw, total, FB, MB, CB);
    k_dinv<<<(N + 255) / 256, 256, 0, stream>>>(cnt, dinv, N);

    int LB = (N + 63) / 64;
    // layer 1: fused agg+gemm: gather xb -> h1 table (f16) in ab
    k_layer<1><<<LB, 256, 0, stream>>>(xb, wt1, b1, al, m1, dinv, cnt, csr, ab, N);
    // layer 2: fused agg+gemm: gather ab -> d_out (f32)
    k_layer<0><<<LB, 256, 0, stream>>>(ab, wt2, b2, al, m2, dinv, cnt, csr, out, N);
}